// Round 4
// baseline (284.218 us; speedup 1.0000x reference)
//
#include <hip/hip_runtime.h>
#include <stdint.h>

typedef unsigned short u16;
typedef __bf16 bf16x8 __attribute__((ext_vector_type(8)));
typedef float f32x4 __attribute__((ext_vector_type(4)));

#define BB 2
#define TT 2048
#define CC 768
#define HH 12
#define HD 64
#define MTOT (BB*TT)   // 4096
#define N_QKV (3*CC)   // 2304
#define NSPLIT 2
#define NROWS (BB*HH*TT)   // 49152

__device__ __forceinline__ u16 f2bf(float f) {
    uint32_t u = __builtin_bit_cast(uint32_t, f);
    u = (u + 0x7fffu + ((u >> 16) & 1u)) >> 16;
    return (u16)u;
}
__device__ __forceinline__ float bf2f(u16 h) {
    return __builtin_bit_cast(float, (uint32_t)h << 16);
}

union U16x8 { uint4 v; u16 s[8]; };

__device__ __forceinline__ void gl_lds16(const u16* g, u16* l) {
    __builtin_amdgcn_global_load_lds(
        (const __attribute__((address_space(1))) uint32_t*)g,
        (__attribute__((address_space(3))) uint32_t*)l, 16, 0, 0);
}

// ---------------- fp32 -> bf16 conversion (4 elems/thread) ----------------
__global__ void k_cvt(const float* __restrict__ src, u16* __restrict__ dst, int n4) {
    int i = blockIdx.x * blockDim.x + threadIdx.x;
    if (i >= n4) return;
    float4 v = reinterpret_cast<const float4*>(src)[i];
    uint lo = (uint)f2bf(v.x) | ((uint)f2bf(v.y) << 16);
    uint hi = (uint)f2bf(v.z) | ((uint)f2bf(v.w) << 16);
    reinterpret_cast<uint2*>(dst)[i] = make_uint2(lo, hi);
}

// ---------------- mask -> additive bias ----------------
__global__ void k_mask(const int* __restrict__ m, float* __restrict__ o, int n) {
    int i = blockIdx.x * blockDim.x + threadIdx.x;
    if (i < n) o[i] = (m[i] == 0) ? -1e30f : 0.0f;
}

// ---------------- pack biases bq|bk|bv -> bqkv[2304] ----------------
__global__ void k_packb(const float* __restrict__ bq, const float* __restrict__ bk,
                        const float* __restrict__ bv, float* __restrict__ o) {
    int i = blockIdx.x * blockDim.x + threadIdx.x;
    if (i < CC) o[i] = bq[i];
    else if (i < 2 * CC) o[i] = bk[i - CC];
    else if (i < 3 * CC) o[i] = bv[i - 2 * CC];
}

// ---------------- GEMM: C = A @ W^T + bias (m97-style staging) ----------------
#define GBM 128
#define GBN 128
#define GBK 32

__global__ __launch_bounds__(256)
void k_gemm(const u16* __restrict__ A, const u16* __restrict__ W,
            const float* __restrict__ bias, int K, int N, int mode,
            u16* __restrict__ outQ, u16* __restrict__ outK, u16* __restrict__ outVt,
            float* __restrict__ outLin)
{
    __shared__ alignas(16) u16 As[GBM][GBK];
    __shared__ alignas(16) u16 Bs[GBN][GBK];

    const int tid  = threadIdx.x;
    const int lane = tid & 63;
    const int wave = tid >> 6;
    const int m0 = blockIdx.y * GBM;
    const int n0 = blockIdx.x * GBN;
    const int wm = (wave >> 1) * 64;
    const int wn = (wave & 1) * 64;

    f32x4 acc[4][4];
#pragma unroll
    for (int m = 0; m < 4; ++m)
#pragma unroll
        for (int n = 0; n < 4; ++n)
            acc[m][n] = f32x4{0.f, 0.f, 0.f, 0.f};

    const int lrow = lane >> 2;        // 0..15
    const int lcol = (lane & 3) * 8;   // 0,8,16,24

    for (int k0 = 0; k0 < K; k0 += GBK) {
        __syncthreads();
        {
            const int r0 = wave * 32;
            gl_lds16(A + (size_t)(m0 + r0 + lrow) * K + k0 + lcol,      &As[r0][0]);
            gl_lds16(A + (size_t)(m0 + r0 + 16 + lrow) * K + k0 + lcol, &As[r0 + 16][0]);
            gl_lds16(W + (size_t)(n0 + r0 + lrow) * K + k0 + lcol,      &Bs[r0][0]);
            gl_lds16(W + (size_t)(n0 + r0 + 16 + lrow) * K + k0 + lcol, &Bs[r0 + 16][0]);
        }
        __syncthreads();

        bf16x8 af[4], bfb[4];
#pragma unroll
        for (int m = 0; m < 4; ++m)
            af[m] = *reinterpret_cast<const bf16x8*>(&As[wm + m * 16 + (lane & 15)][(lane >> 4) * 8]);
#pragma unroll
        for (int n = 0; n < 4; ++n)
            bfb[n] = *reinterpret_cast<const bf16x8*>(&Bs[wn + n * 16 + (lane & 15)][(lane >> 4) * 8]);
#pragma unroll
        for (int m = 0; m < 4; ++m)
#pragma unroll
            for (int n = 0; n < 4; ++n)
                acc[m][n] = __builtin_amdgcn_mfma_f32_16x16x32_bf16(af[m], bfb[n], acc[m][n], 0, 0, 0);
    }

    const int col   = lane & 15;
    const int rbase = (lane >> 4) * 4;
#pragma unroll
    for (int m = 0; m < 4; ++m) {
#pragma unroll
        for (int n = 0; n < 4; ++n) {
            const int gn = n0 + wn + n * 16 + col;
            const float bv = bias[gn];
#pragma unroll
            for (int j = 0; j < 4; ++j) {
                const int gm = m0 + wm + m * 16 + rbase + j;
                const float val = acc[m][n][j] + bv;
                if (mode == 1) {
                    outLin[(size_t)gm * N + gn] = val;
                } else {
                    const int proj = gn / CC;           // 0=q,1=k,2=v
                    const int c = gn - proj * CC;
                    const int h = c >> 6, hd = c & 63;
                    const int b = gm >> 11, t = gm & (TT - 1);
                    if (proj == 0)
                        outQ[((size_t)(b * HH + h) * TT + t) * HD + hd] = f2bf(val);
                    else if (proj == 1)
                        outK[((size_t)(b * HH + h) * TT + t) * HD + hd] = f2bf(val);
                    else
                        outVt[((size_t)(b * HH + h) * HD + hd) * TT + t] = f2bf(val);
                }
            }
        }
    }
}

// ---------------- flash attention, key-split flash-decoding ----------------
// grid: 3072 blocks x 64 threads. 1 wave/block, 32 queries, 1024 keys (8 x 128-key tiles).
// Writes unnormalized partial O (fp32) + running m,l per row to workspace.
__global__ __launch_bounds__(64)
void k_attn(const u16* __restrict__ Qh, const u16* __restrict__ Kh,
            const u16* __restrict__ Vt, const float* __restrict__ maskb,
            float* __restrict__ Opart, float* __restrict__ Mpart, float* __restrict__ Lpart)
{
    __shared__ alignas(16) u16 Ps[32][136];   // row stride 272B -> <=2-way conflicts

    const int lane = threadIdx.x;
    // XCD-chunked swizzle: 3072 blocks, 384 consecutive virtual blocks per XCD
    const int raw  = blockIdx.x;
    const int virt = (raw & 7) * 384 + (raw >> 3);
    const int bh  = virt >> 7;            // 128 blocks per head (64 q-tiles x 2 splits)
    const int rem = virt & 127;
    const int q0  = (rem >> 1) * 32;
    const int sp  = rem & 1;
    const int kt0 = sp * (TT / NSPLIT);

    const u16* Qp = Qh + (size_t)bh * TT * HD;
    const u16* Kp = Kh + (size_t)bh * TT * HD;
    const u16* Vp = Vt + (size_t)bh * HD * TT;
    const int b = bh / HH;
    const float* mrow = maskb + b * TT;

    const int l15 = lane & 15;
    const int lg  = lane >> 4;        // 0..3

    // Q fragments, pre-scaled by 1/sqrt(64)=0.125
    bf16x8 qf[2][2];
#pragma unroll
    for (int m = 0; m < 2; ++m)
#pragma unroll
        for (int ks = 0; ks < 2; ++ks) {
            U16x8 t;
            t.v = *reinterpret_cast<const uint4*>(
                Qp + (size_t)(q0 + m * 16 + l15) * HD + ks * 32 + lg * 8);
            U16x8 o;
#pragma unroll
            for (int j = 0; j < 8; ++j) o.s[j] = f2bf(bf2f(t.s[j]) * 0.125f);
            qf[m][ks] = __builtin_bit_cast(bf16x8, o.v);
        }

    f32x4 oacc[2][4];
#pragma unroll
    for (int m = 0; m < 2; ++m)
#pragma unroll
        for (int n = 0; n < 4; ++n) oacc[m][n] = f32x4{0.f, 0.f, 0.f, 0.f};
    float mrun[2][4], lrun[2][4];
#pragma unroll
    for (int m = 0; m < 2; ++m)
#pragma unroll
        for (int j = 0; j < 4; ++j) { mrun[m][j] = -1e30f; lrun[m][j] = 0.f; }

    for (int kt = kt0; kt < kt0 + TT / NSPLIT; kt += 128) {
        // ---- S = (Q*0.125) @ K^T   (32q x 128k) ----
        f32x4 sacc[2][8];
#pragma unroll
        for (int m = 0; m < 2; ++m)
#pragma unroll
            for (int n = 0; n < 8; ++n) sacc[m][n] = f32x4{0.f, 0.f, 0.f, 0.f};
#pragma unroll
        for (int ks = 0; ks < 2; ++ks) {
            uint4 kfr[8];
#pragma unroll
            for (int n = 0; n < 8; ++n)
                kfr[n] = *reinterpret_cast<const uint4*>(
                    Kp + (size_t)(kt + n * 16 + l15) * HD + ks * 32 + lg * 8);
#pragma unroll
            for (int n = 0; n < 8; ++n) {
                bf16x8 kf = __builtin_bit_cast(bf16x8, kfr[n]);
#pragma unroll
                for (int m = 0; m < 2; ++m)
                    sacc[m][n] = __builtin_amdgcn_mfma_f32_16x16x32_bf16(qf[m][ks], kf, sacc[m][n], 0, 0, 0);
            }
        }

        // ---- online softmax ----
        float mbv[8];
#pragma unroll
        for (int n = 0; n < 8; ++n) mbv[n] = mrow[kt + n * 16 + l15];

        float tmax[2][4];
#pragma unroll
        for (int m = 0; m < 2; ++m)
#pragma unroll
            for (int j = 0; j < 4; ++j) tmax[m][j] = -1e30f;
#pragma unroll
        for (int m = 0; m < 2; ++m)
#pragma unroll
            for (int n = 0; n < 8; ++n)
#pragma unroll
                for (int j = 0; j < 4; ++j) {
                    float s = sacc[m][n][j] + mbv[n];
                    sacc[m][n][j] = s;
                    tmax[m][j] = fmaxf(tmax[m][j], s);
                }
#pragma unroll
        for (int off = 1; off < 16; off <<= 1)
#pragma unroll
            for (int m = 0; m < 2; ++m)
#pragma unroll
                for (int j = 0; j < 4; ++j)
                    tmax[m][j] = fmaxf(tmax[m][j], __shfl_xor(tmax[m][j], off));

        float scl[2][4];
#pragma unroll
        for (int m = 0; m < 2; ++m)
#pragma unroll
            for (int j = 0; j < 4; ++j) {
                float mnew = fmaxf(mrun[m][j], tmax[m][j]);
                scl[m][j] = __expf(mrun[m][j] - mnew);
                mrun[m][j] = mnew;
            }

        float rs[2][4];
#pragma unroll
        for (int m = 0; m < 2; ++m)
#pragma unroll
            for (int j = 0; j < 4; ++j) rs[m][j] = 0.f;
#pragma unroll
        for (int m = 0; m < 2; ++m)
#pragma unroll
            for (int n = 0; n < 8; ++n)
#pragma unroll
                for (int j = 0; j < 4; ++j) {
                    // masked s ~ -1e30: exp underflows to 0 naturally
                    float p = __expf(sacc[m][n][j] - mrun[m][j]);
                    sacc[m][n][j] = p;
                    rs[m][j] += p;
                }
#pragma unroll
        for (int off = 1; off < 16; off <<= 1)
#pragma unroll
            for (int m = 0; m < 2; ++m)
#pragma unroll
                for (int j = 0; j < 4; ++j) rs[m][j] += __shfl_xor(rs[m][j], off);
#pragma unroll
        for (int m = 0; m < 2; ++m)
#pragma unroll
            for (int j = 0; j < 4; ++j) lrun[m][j] = lrun[m][j] * scl[m][j] + rs[m][j];

        // ---- P -> LDS (per-wave, no barrier needed) ----
#pragma unroll
        for (int m = 0; m < 2; ++m)
#pragma unroll
            for (int n = 0; n < 8; ++n)
#pragma unroll
                for (int j = 0; j < 4; ++j)
                    Ps[m * 16 + lg * 4 + j][n * 16 + l15] = f2bf(sacc[m][n][j]);

        // ---- O = O*scl + P @ V ----
#pragma unroll
        for (int m = 0; m < 2; ++m)
#pragma unroll
            for (int n = 0; n < 4; ++n)
#pragma unroll
                for (int j = 0; j < 4; ++j) oacc[m][n][j] *= scl[m][j];

#pragma unroll
        for (int ks2 = 0; ks2 < 4; ++ks2) {
            bf16x8 pf[2];
#pragma unroll
            for (int m = 0; m < 2; ++m)
                pf[m] = *reinterpret_cast<const bf16x8*>(&Ps[m * 16 + l15][ks2 * 32 + lg * 8]);
            uint4 vfr[4];
#pragma unroll
            for (int n = 0; n < 4; ++n)
                vfr[n] = *reinterpret_cast<const uint4*>(
                    Vp + (size_t)(n * 16 + l15) * TT + kt + ks2 * 32 + lg * 8);
#pragma unroll
            for (int n = 0; n < 4; ++n) {
                bf16x8 vf = __builtin_bit_cast(bf16x8, vfr[n]);
#pragma unroll
                for (int m = 0; m < 2; ++m)
                    oacc[m][n] = __builtin_amdgcn_mfma_f32_16x16x32_bf16(pf[m], vf, oacc[m][n], 0, 0, 0);
            }
        }
    }

    // ---- epilogue: write partial O (fp32, unnormalized) + m,l ----
    const size_t rbase_ = (size_t)sp * NROWS + (size_t)bh * TT;
#pragma unroll
    for (int m = 0; m < 2; ++m)
#pragma unroll
        for (int n = 0; n < 4; ++n)
#pragma unroll
            for (int j = 0; j < 4; ++j) {
                const size_t r = rbase_ + q0 + m * 16 + lg * 4 + j;
                Opart[r * HD + n * 16 + l15] = oacc[m][n][j];
            }
    if (l15 == 0) {
#pragma unroll
        for (int m = 0; m < 2; ++m)
#pragma unroll
            for (int j = 0; j < 4; ++j) {
                const size_t r = rbase_ + q0 + m * 16 + lg * 4 + j;
                Mpart[r] = mrun[m][j];
                Lpart[r] = lrun[m][j];
            }
    }
}

// ---------------- combine partials -> y_bf ----------------
// 4 waves/block, 1 row per wave, lane d = head dim.
__global__ __launch_bounds__(256)
void k_comb(const float* __restrict__ Opart, const float* __restrict__ Mpart,
            const float* __restrict__ Lpart, u16* __restrict__ Y)
{
    const int wave = threadIdx.x >> 6;
    const int d    = threadIdx.x & 63;
    const size_t r = (size_t)blockIdx.x * 4 + wave;
    const float m1 = Mpart[r],         l1 = Lpart[r];
    const float m2 = Mpart[NROWS + r], l2 = Lpart[NROWS + r];
    const float mm = fmaxf(m1, m2);
    const float w1 = __expf(m1 - mm), w2 = __expf(m2 - mm);
    const float l  = l1 * w1 + l2 * w2;
    const float o  = Opart[r * HD + d] * w1 + Opart[((size_t)NROWS + r) * HD + d] * w2;
    const int bh = (int)(r >> 11), t = (int)(r & (TT - 1));
    const int b = bh / HH, h = bh % HH;
    Y[((size_t)b * TT + t) * CC + h * 64 + d] = f2bf(o / l);
}

// ---------------- launcher ----------------
extern "C" void kernel_launch(void* const* d_in, const int* in_sizes, int n_in,
                              void* d_out, int out_size, void* d_ws, size_t ws_size,
                              hipStream_t stream)
{
    const float* x    = (const float*)d_in[0];
    const int*   mask = (const int*)d_in[1];
    const float* Wq   = (const float*)d_in[2];
    const float* bq   = (const float*)d_in[3];
    const float* Wk   = (const float*)d_in[4];
    const float* bk   = (const float*)d_in[5];
    const float* Wv   = (const float*)d_in[6];
    const float* bv   = (const float*)d_in[7];
    const float* Wp   = (const float*)d_in[8];
    const float* bp   = (const float*)d_in[9];
    float* out = (float*)d_out;

    char* w = (char*)d_ws;
    auto alloc = [&](size_t bytes) {
        char* p = w;
        w += (bytes + 255) & ~(size_t)255;
        return p;
    };
    u16* x_bf    = (u16*)alloc((size_t)MTOT * CC * 2);
    u16* wqkv_bf = (u16*)alloc((size_t)3 * CC * CC * 2);
    u16* wp_bf   = (u16*)alloc((size_t)CC * CC * 2);
    u16* qh      = (u16*)alloc((size_t)MTOT * CC * 2);
    u16* kh      = (u16*)alloc((size_t)MTOT * CC * 2);
    u16* vt      = (u16*)alloc((size_t)MTOT * CC * 2);
    u16* y_bf    = (u16*)alloc((size_t)MTOT * CC * 2);
    float* maskb = (float*)alloc((size_t)BB * TT * 4);
    float* bqkv  = (float*)alloc((size_t)N_QKV * 4);
    float* Opart = (float*)alloc((size_t)NSPLIT * NROWS * HD * 4);   // 25.2 MB
    float* Mpart = (float*)alloc((size_t)NSPLIT * NROWS * 4);
    float* Lpart = (float*)alloc((size_t)NSPLIT * NROWS * 4);

    const int NX4 = MTOT * CC / 4;
    k_cvt<<<(NX4 + 255) / 256, 256, 0, stream>>>(x, x_bf, NX4);
    const int NW4 = CC * CC / 4;
    k_cvt<<<(NW4 + 255) / 256, 256, 0, stream>>>(Wq, wqkv_bf, NW4);
    k_cvt<<<(NW4 + 255) / 256, 256, 0, stream>>>(Wk, wqkv_bf + (size_t)CC * CC, NW4);
    k_cvt<<<(NW4 + 255) / 256, 256, 0, stream>>>(Wv, wqkv_bf + (size_t)2 * CC * CC, NW4);
    k_cvt<<<(NW4 + 255) / 256, 256, 0, stream>>>(Wp, wp_bf, NW4);
    k_mask<<<(BB * TT + 255) / 256, 256, 0, stream>>>(mask, maskb, BB * TT);
    k_packb<<<(N_QKV + 255) / 256, 256, 0, stream>>>(bq, bk, bv, bqkv);

    // fused QKV projection: [4096 x 768] @ [2304 x 768]^T
    k_gemm<<<dim3(N_QKV / GBN, MTOT / GBM), 256, 0, stream>>>(
        x_bf, wqkv_bf, bqkv, CC, N_QKV, 0, qh, kh, vt, nullptr);

    k_attn<<<dim3(1536 * NSPLIT), 64, 0, stream>>>(qh, kh, vt, maskb, Opart, Mpart, Lpart);
    k_comb<<<dim3(NROWS / 4), 256, 0, stream>>>(Opart, Mpart, Lpart, y_bf);

    // output projection: fp32 out
    k_gemm<<<dim3(CC / GBN, MTOT / GBM), 256, 0, stream>>>(
        y_bf, wp_bf, bp, CC, CC, 1, nullptr, nullptr, nullptr, out);
}

// Round 7
// 257.552 us; speedup vs baseline: 1.1035x; 1.1035x over previous
//
#include <hip/hip_runtime.h>
#include <stdint.h>

typedef unsigned short u16;
typedef __bf16 bf16x8 __attribute__((ext_vector_type(8)));
typedef float f32x4 __attribute__((ext_vector_type(4)));
typedef float f32x16 __attribute__((ext_vector_type(16)));

#define BB 2
#define TT 2048
#define CC 768
#define HH 12
#define HD 64
#define MTOT (BB*TT)   // 4096
#define N_QKV (3*CC)   // 2304

__device__ __forceinline__ u16 f2bf(float f) {
    uint32_t u = __builtin_bit_cast(uint32_t, f);
    u = (u + 0x7fffu + ((u >> 16) & 1u)) >> 16;
    return (u16)u;
}
__device__ __forceinline__ float bf2f(u16 h) {
    return __builtin_bit_cast(float, (uint32_t)h << 16);
}

union U16x8 { uint4 v; u16 s[8]; };

__device__ __forceinline__ void gl_lds16(const u16* g, u16* l) {
    __builtin_amdgcn_global_load_lds(
        (const __attribute__((address_space(1))) uint32_t*)g,
        (__attribute__((address_space(3))) uint32_t*)l, 16, 0, 0);
}

// ---------------- fp32 -> bf16 conversion (4 elems/thread) ----------------
__global__ void k_cvt(const float* __restrict__ src, u16* __restrict__ dst, int n4) {
    int i = blockIdx.x * blockDim.x + threadIdx.x;
    if (i >= n4) return;
    float4 v = reinterpret_cast<const float4*>(src)[i];
    uint lo = (uint)f2bf(v.x) | ((uint)f2bf(v.y) << 16);
    uint hi = (uint)f2bf(v.z) | ((uint)f2bf(v.w) << 16);
    reinterpret_cast<uint2*>(dst)[i] = make_uint2(lo, hi);
}

// ---------------- mask -> additive bias ----------------
__global__ void k_mask(const int* __restrict__ m, float* __restrict__ o, int n) {
    int i = blockIdx.x * blockDim.x + threadIdx.x;
    if (i < n) o[i] = (m[i] == 0) ? -1e30f : 0.0f;
}

// ---------------- pack biases bq|bk|bv -> bqkv[2304] ----------------
__global__ void k_packb(const float* __restrict__ bq, const float* __restrict__ bk,
                        const float* __restrict__ bv, float* __restrict__ o) {
    int i = blockIdx.x * blockDim.x + threadIdx.x;
    if (i < CC) o[i] = bq[i];
    else if (i < 2 * CC) o[i] = bk[i - CC];
    else if (i < 3 * CC) o[i] = bv[i - 2 * CC];
}

// ---------------- GEMM: C = A @ W^T + bias (2-phase prefetch, dbuf LDS) ----
#define GBM 128
#define GBN 128
#define GBK 32

__global__ __launch_bounds__(256)
void k_gemm(const u16* __restrict__ A, const u16* __restrict__ W,
            const float* __restrict__ bias, int K, int N, int mode,
            u16* __restrict__ outQ, u16* __restrict__ outK, u16* __restrict__ outVt,
            float* __restrict__ outLin)
{
    __shared__ alignas(16) u16 As[2][GBM][GBK];
    __shared__ alignas(16) u16 Bs[2][GBM][GBK];

    const int tid  = threadIdx.x;
    const int lane = tid & 63;
    const int wave = tid >> 6;
    const int m0 = blockIdx.y * GBM;
    const int n0 = blockIdx.x * GBN;
    const int wm = (wave >> 1) * 64;
    const int wn = (wave & 1) * 64;

    f32x4 acc[4][4];
#pragma unroll
    for (int m = 0; m < 4; ++m)
#pragma unroll
        for (int n = 0; n < 4; ++n)
            acc[m][n] = f32x4{0.f, 0.f, 0.f, 0.f};

    const int lrow = lane >> 2;        // 0..15
    const int lcol = (lane & 3) * 8;   // 0,8,16,24

    auto stage = [&](int buf, int k0) {
        const int r0 = wave * 32;
        gl_lds16(A + (size_t)(m0 + r0 + lrow) * K + k0 + lcol,      &As[buf][r0][0]);
        gl_lds16(A + (size_t)(m0 + r0 + 16 + lrow) * K + k0 + lcol, &As[buf][r0 + 16][0]);
        gl_lds16(W + (size_t)(n0 + r0 + lrow) * K + k0 + lcol,      &Bs[buf][r0][0]);
        gl_lds16(W + (size_t)(n0 + r0 + 16 + lrow) * K + k0 + lcol, &Bs[buf][r0 + 16][0]);
    };

    const int nt = K / GBK;
    stage(0, 0);
    __syncthreads();           // drains vmcnt -> buf0 ready

    int cur = 0;
    for (int t = 0; t < nt; ++t) {
        if (t + 1 < nt) stage(cur ^ 1, (t + 1) * GBK);   // prefetch overlaps compute

        bf16x8 af[4], bfb[4];
#pragma unroll
        for (int m = 0; m < 4; ++m)
            af[m] = *reinterpret_cast<const bf16x8*>(&As[cur][wm + m * 16 + (lane & 15)][(lane >> 4) * 8]);
#pragma unroll
        for (int n = 0; n < 4; ++n)
            bfb[n] = *reinterpret_cast<const bf16x8*>(&Bs[cur][wn + n * 16 + (lane & 15)][(lane >> 4) * 8]);
#pragma unroll
        for (int m = 0; m < 4; ++m)
#pragma unroll
            for (int n = 0; n < 4; ++n)
                acc[m][n] = __builtin_amdgcn_mfma_f32_16x16x32_bf16(af[m], bfb[n], acc[m][n], 0, 0, 0);

        __syncthreads();       // single barrier per K-step (drains prefetch too)
        cur ^= 1;
    }

    const int col   = lane & 15;
    const int rbase = (lane >> 4) * 4;
#pragma unroll
    for (int m = 0; m < 4; ++m) {
#pragma unroll
        for (int n = 0; n < 4; ++n) {
            const int gn = n0 + wn + n * 16 + col;
            const float bv = bias[gn];
#pragma unroll
            for (int j = 0; j < 4; ++j) {
                const int gm = m0 + wm + m * 16 + rbase + j;
                const float val = acc[m][n][j] + bv;
                if (mode == 1) {
                    outLin[(size_t)gm * N + gn] = val;
                } else {
                    const int proj = gn / CC;           // 0=q,1=k,2=v
                    const int c = gn - proj * CC;
                    const int h = c >> 6, hd = c & 63;
                    const int b = gm >> 11, t = gm & (TT - 1);
                    if (proj == 0)
                        outQ[((size_t)(b * HH + h) * TT + t) * HD + hd] = f2bf(val);
                    else if (proj == 1)
                        outK[((size_t)(b * HH + h) * TT + t) * HD + hd] = f2bf(val);
                    else
                        outVt[((size_t)(b * HH + h) * HD + hd) * TT + t] = f2bf(val);
                }
            }
        }
    }
}

// ---------------- flash attention: swapped-operand 32x32, in-register softmax --
// grid: 1536 blocks x 64 threads. 1 wave/block, 32 queries/wave, 32-key steps.
// S = mfma(K, Q): D[row=key][col=query] -> each lane owns one query, 16 keys in-reg.
// PV = mfma(V^T, P): O^T[d][q]. No LDS, no barriers.
__global__ __launch_bounds__(64)
void k_attn(const u16* __restrict__ Qh, const u16* __restrict__ Kh,
            const u16* __restrict__ Vt, const float* __restrict__ maskb,
            u16* __restrict__ Y)
{
    const int lane = threadIdx.x;
    const int raw  = blockIdx.x;
    const int virt = (raw & 7) * 192 + (raw >> 3);   // XCD-chunked, bijective (1536=8*192)
    const int bh = virt >> 6;
    const int b  = bh / HH, h = bh % HH;
    const int q0 = (virt & 63) * 32;

    const int l31 = lane & 31;
    const int hi  = lane >> 5;          // 0/1

    const u16* Qp = Qh + (size_t)bh * TT * HD;
    const u16* Kp = Kh + (size_t)bh * TT * HD;
    const u16* Vp = Vt + (size_t)bh * HD * TT;
    const float* mrow = maskb + b * TT;

    // Q as B-operand (pre-scaled by 1/sqrt(64)=0.125):
    // qf[i] elem j = Q[q0+l31][16i + hi*8 + j]
    bf16x8 qf[4];
#pragma unroll
    for (int i = 0; i < 4; ++i) {
        U16x8 t;
        t.v = *reinterpret_cast<const uint4*>(Qp + (size_t)(q0 + l31) * HD + 16 * i + hi * 8);
        U16x8 o;
#pragma unroll
        for (int j = 0; j < 8; ++j) o.s[j] = f2bf(bf2f(t.s[j]) * 0.125f);
        qf[i] = __builtin_bit_cast(bf16x8, o.v);
    }

    f32x16 oacc0, oacc1;               // O^T tiles: d 0..31 / 32..63
#pragma unroll
    for (int r = 0; r < 16; ++r) { oacc0[r] = 0.f; oacc1[r] = 0.f; }
    float mrun = -1e30f, lrun = 0.f;

    for (int kt = 0; kt < TT; kt += 32) {
        // ---- S = K @ Q^T : lane holds S[key=(r&3)+8*(r>>2)+4*hi][q=l31] ----
        f32x16 s;
#pragma unroll
        for (int r = 0; r < 16; ++r) s[r] = 0.f;
#pragma unroll
        for (int i = 0; i < 4; ++i) {
            uint4 kv = *reinterpret_cast<const uint4*>(
                Kp + (size_t)(kt + l31) * HD + 16 * i + hi * 8);
            s = __builtin_amdgcn_mfma_f32_32x32x16_bf16(
                __builtin_bit_cast(bf16x8, kv), qf[i], s, 0, 0, 0);
        }

        // ---- mask bias (broadcast loads: addr independent of l31) ----
        float mbf[16];
#pragma unroll
        for (int r2 = 0; r2 < 4; ++r2) {
            float4 v = *reinterpret_cast<const float4*>(mrow + kt + 8 * r2 + 4 * hi);
            mbf[4 * r2 + 0] = v.x; mbf[4 * r2 + 1] = v.y;
            mbf[4 * r2 + 2] = v.z; mbf[4 * r2 + 3] = v.w;
        }
#pragma unroll
        for (int r = 0; r < 16; ++r) s[r] += mbf[r];

        // ---- online softmax: in-lane tree + one xor-32 exchange ----
        float m8[8];
#pragma unroll
        for (int r = 0; r < 8; ++r) m8[r] = fmaxf(s[r], s[r + 8]);
        float m4[4];
#pragma unroll
        for (int r = 0; r < 4; ++r) m4[r] = fmaxf(m8[r], m8[r + 4]);
        float tm = fmaxf(fmaxf(m4[0], m4[1]), fmaxf(m4[2], m4[3]));
        tm = fmaxf(tm, __shfl_xor(tm, 32));

        float mnew = fmaxf(mrun, tm);
        float scl = __expf(mrun - mnew);
        mrun = mnew;

        float p[16];
#pragma unroll
        for (int r = 0; r < 16; ++r) p[r] = __expf(s[r] - mrun);
        float s8[8];
#pragma unroll
        for (int r = 0; r < 8; ++r) s8[r] = p[r] + p[r + 8];
        float s4[4];
#pragma unroll
        for (int r = 0; r < 4; ++r) s4[r] = s8[r] + s8[r + 4];
        float rs = (s4[0] + s4[1]) + (s4[2] + s4[3]);
        rs += __shfl_xor(rs, 32);
        lrun = lrun * scl + rs;

        // ---- rescale O ----
#pragma unroll
        for (int r = 0; r < 16; ++r) { oacc0[r] *= scl; oacc1[r] *= scl; }

        // ---- pack P to bf16 pairs: quad g (regs 4g..4g+3) = keys 8g+4*hi+0..3 ----
        uint32_t pk[8];
#pragma unroll
        for (int g = 0; g < 4; ++g) {
            asm("v_cvt_pk_bf16_f32 %0, %1, %2"
                : "=v"(pk[2 * g]) : "v"(p[4 * g]), "v"(p[4 * g + 1]));
            asm("v_cvt_pk_bf16_f32 %0, %1, %2"
                : "=v"(pk[2 * g + 1]) : "v"(p[4 * g + 2]), "v"(p[4 * g + 3]));
        }

        // ---- PV: O^T += V^T @ P  (B-frag keys = 16kk + 8*hi + j) ----
#pragma unroll
        for (int kk = 0; kk < 2; ++kk) {
            // exchange with partner lane (xor 32): lo needs partner pk[4kk..4kk+1],
            // hi needs partner pk[4kk+2..4kk+3] -> pre-select then swap.
            uint32_t sA = (uint32_t)__shfl_xor((int)(hi ? pk[4 * kk]     : pk[4 * kk + 2]), 32);
            uint32_t sB = (uint32_t)__shfl_xor((int)(hi ? pk[4 * kk + 1] : pk[4 * kk + 3]), 32);
            uint4 bw;
            bw.x = hi ? sA : pk[4 * kk];
            bw.y = hi ? sB : pk[4 * kk + 1];
            bw.z = hi ? pk[4 * kk + 2] : sA;
            bw.w = hi ? pk[4 * kk + 3] : sB;
            bf16x8 pb = __builtin_bit_cast(bf16x8, bw);

            uint4 v0 = *reinterpret_cast<const uint4*>(
                Vp + (size_t)l31 * TT + kt + 16 * kk + hi * 8);
            uint4 v1 = *reinterpret_cast<const uint4*>(
                Vp + (size_t)(32 + l31) * TT + kt + 16 * kk + hi * 8);
            oacc0 = __builtin_amdgcn_mfma_f32_32x32x16_bf16(
                __builtin_bit_cast(bf16x8, v0), pb, oacc0, 0, 0, 0);
            oacc1 = __builtin_amdgcn_mfma_f32_32x32x16_bf16(
                __builtin_bit_cast(bf16x8, v1), pb, oacc1, 0, 0, 0);
        }
    }

    // ---- epilogue: y[b][t=q0+l31][h*64 + d], d = dt*32 + (r&3)+8*(r>>2)+4*hi ----
    const float inv = 1.0f / lrun;
    u16* yrow = Y + ((size_t)b * TT + q0 + l31) * CC + h * 64;
#pragma unroll
    for (int dt = 0; dt < 2; ++dt) {
        f32x16 oa = dt ? oacc1 : oacc0;
#pragma unroll
        for (int r2 = 0; r2 < 4; ++r2) {
            ushort4 w;
            w.x = f2bf(oa[4 * r2 + 0] * inv);
            w.y = f2bf(oa[4 * r2 + 1] * inv);
            w.z = f2bf(oa[4 * r2 + 2] * inv);
            w.w = f2bf(oa[4 * r2 + 3] * inv);
            *reinterpret_cast<ushort4*>(yrow + dt * 32 + 8 * r2 + 4 * hi) = w;
        }
    }
}

// ---------------- launcher ----------------
extern "C" void kernel_launch(void* const* d_in, const int* in_sizes, int n_in,
                              void* d_out, int out_size, void* d_ws, size_t ws_size,
                              hipStream_t stream)
{
    const float* x    = (const float*)d_in[0];
    const int*   mask = (const int*)d_in[1];
    const float* Wq   = (const float*)d_in[2];
    const float* bq   = (const float*)d_in[3];
    const float* Wk   = (const float*)d_in[4];
    const float* bk   = (const float*)d_in[5];
    const float* Wv   = (const float*)d_in[6];
    const float* bv   = (const float*)d_in[7];
    const float* Wp   = (const float*)d_in[8];
    const float* bp   = (const float*)d_in[9];
    float* out = (float*)d_out;

    char* w = (char*)d_ws;
    auto alloc = [&](size_t bytes) {
        char* p = w;
        w += (bytes + 255) & ~(size_t)255;
        return p;
    };
    u16* x_bf    = (u16*)alloc((size_t)MTOT * CC * 2);
    u16* wqkv_bf = (u16*)alloc((size_t)3 * CC * CC * 2);
    u16* wp_bf   = (u16*)alloc((size_t)CC * CC * 2);
    u16* qh      = (u16*)alloc((size_t)MTOT * CC * 2);
    u16* kh      = (u16*)alloc((size_t)MTOT * CC * 2);
    u16* vt      = (u16*)alloc((size_t)MTOT * CC * 2);
    u16* y_bf    = (u16*)alloc((size_t)MTOT * CC * 2);
    float* maskb = (float*)alloc((size_t)BB * TT * 4);
    float* bqkv  = (float*)alloc((size_t)N_QKV * 4);

    const int NX4 = MTOT * CC / 4;
    k_cvt<<<(NX4 + 255) / 256, 256, 0, stream>>>(x, x_bf, NX4);
    const int NW4 = CC * CC / 4;
    k_cvt<<<(NW4 + 255) / 256, 256, 0, stream>>>(Wq, wqkv_bf, NW4);
    k_cvt<<<(NW4 + 255) / 256, 256, 0, stream>>>(Wk, wqkv_bf + (size_t)CC * CC, NW4);
    k_cvt<<<(NW4 + 255) / 256, 256, 0, stream>>>(Wv, wqkv_bf + (size_t)2 * CC * CC, NW4);
    k_cvt<<<(NW4 + 255) / 256, 256, 0, stream>>>(Wp, wp_bf, NW4);
    k_mask<<<(BB * TT + 255) / 256, 256, 0, stream>>>(mask, maskb, BB * TT);
    k_packb<<<(N_QKV + 255) / 256, 256, 0, stream>>>(bq, bk, bv, bqkv);

    // fused QKV projection: [4096 x 768] @ [2304 x 768]^T
    k_gemm<<<dim3(N_QKV / GBN, MTOT / GBM), 256, 0, stream>>>(
        x_bf, wqkv_bf, bqkv, CC, N_QKV, 0, qh, kh, vt, nullptr);

    k_attn<<<dim3(1536), 64, 0, stream>>>(qh, kh, vt, maskb, y_bf);

    // output projection: fp32 out
    k_gemm<<<dim3(CC / GBN, MTOT / GBM), 256, 0, stream>>>(
        y_bf, wp_bf, bp, CC, CC, 1, nullptr, nullptr, nullptr, out);
}